// Round 1
// 570.920 us; speedup vs baseline: 1.7721x; 1.7721x over previous
//
#include <hip/hip_runtime.h>

typedef __attribute__((ext_vector_type(8))) short short8;
typedef __attribute__((ext_vector_type(4))) float floatx4;

#define B_ 2
#define S_ 2048
#define E_ 2048
#define H_ 16
#define D_ 128

#define NEG_S  (-3.0e4f)
#define LOG2E  1.4426950408889634f

__device__ inline float bf2f(unsigned short u) {
    union { unsigned int i; float f; } v; v.i = ((unsigned int)u) << 16; return v.f;
}
__device__ inline unsigned short f2bf(float f) {
    union { float f; unsigned int i; } v; v.f = f;
    unsigned int r = v.i + 0x7FFFu + ((v.i >> 16) & 1u);
    return (unsigned short)(r >> 16);
}

// async global->LDS, 16B per lane. LDS dest is wave-uniform base + lane*16.
__device__ inline void gload_lds16(const void* g, void* l) {
    __builtin_amdgcn_global_load_lds((__attribute__((address_space(1))) void*)(void*)g,
                                     (__attribute__((address_space(3))) void*)l, 16, 0, 0);
}

// Precompute RoPE cos/sin tables: [S][D/2] fp32. 1 MB total.
__global__ void rope_tab(float* __restrict__ cosT, float* __restrict__ sinT) {
    int idx = blockIdx.x * 256 + threadIdx.x;   // 2048*64 entries
    int s = idx >> 6, j = idx & 63;
    float inv = exp2f(-(float)(2 * j) * (13.287712379549449f / 128.0f));
    float ang = (float)s * inv;
    cosT[idx] = cosf(ang);
    sinT[idx] = sinf(ang);
}

// fp32 -> bf16, 8 elems/thread, exact-sized grids.
__global__ __launch_bounds__(256) void cvt_bf16(const float* __restrict__ in,
                                                unsigned short* __restrict__ out, int n8) {
    int i = blockIdx.x * 256 + threadIdx.x;
    if (i >= n8) return;
    float4 f0 = *(const float4*)(in + (size_t)i * 8);
    float4 f1 = *(const float4*)(in + (size_t)i * 8 + 4);
    unsigned short u[8] = {f2bf(f0.x), f2bf(f0.y), f2bf(f0.z), f2bf(f0.w),
                           f2bf(f1.x), f2bf(f1.y), f2bf(f1.z), f2bf(f1.w)};
    *(uint4*)(out + (size_t)i * 8) = *(uint4*)u;
}

// out_k fp32 [B][H][S][D] -> Kr bf16 same layout, RoPE applied once.
__global__ __launch_bounds__(256) void prep_k(const float* __restrict__ K,
                                              unsigned short* __restrict__ Kr,
                                              const float* __restrict__ cosT,
                                              const float* __restrict__ sinT) {
    int idx = blockIdx.x * 256 + threadIdx.x;   // B*H*S*16 = 1,048,576
    int g = idx & 15;
    int s = (idx >> 4) & (S_ - 1);
    const float* src = K + (size_t)idx * 8;
    float4 f0 = *(const float4*)src;
    float4 f1 = *(const float4*)(src + 4);
    float xs[8] = {f0.x, f0.y, f0.z, f0.w, f1.x, f1.y, f1.z, f1.w};
    unsigned short u[8];
    int jb = g * 4;
#pragma unroll
    for (int i = 0; i < 4; i++) {
        float c = cosT[s * 64 + jb + i], sn = sinT[s * 64 + jb + i];
        float x1 = xs[2 * i], x2 = xs[2 * i + 1];
        u[2 * i]     = f2bf(x1 * c - x2 * sn);
        u[2 * i + 1] = f2bf(x1 * sn + x2 * c);
    }
    *(uint4*)(Kr + (size_t)idx * 8) = *(uint4*)u;
}

// out_v fp32 [B][H][S][D] -> Vt bf16 [B][H][D][S] (transposed via LDS).
__global__ __launch_bounds__(256) void prep_v(const float* __restrict__ V,
                                              unsigned short* __restrict__ Vt) {
    __shared__ unsigned short Ls[64][130];
    int bh = blockIdx.y;
    int s0 = blockIdx.x * 64;
    int t = threadIdx.x;
    const float* src = V + ((size_t)bh * S_ + s0) * D_;
#pragma unroll
    for (int it = 0; it < 4; it++) {
        int r = it * 16 + (t >> 4), d0 = (t & 15) * 8;
        float4 f0 = *(const float4*)&src[(size_t)r * D_ + d0];
        float4 f1 = *(const float4*)&src[(size_t)r * D_ + d0 + 4];
        unsigned short u[8] = {f2bf(f0.x), f2bf(f0.y), f2bf(f0.z), f2bf(f0.w),
                               f2bf(f1.x), f2bf(f1.y), f2bf(f1.z), f2bf(f1.w)};
#pragma unroll
        for (int i = 0; i < 8; i++) Ls[r][d0 + i] = u[i];
    }
    __syncthreads();
    unsigned short* dst = Vt + (size_t)bh * D_ * S_;
#pragma unroll
    for (int it = 0; it < 4; it++) {
        int d = it * 32 + (t >> 3), ss = (t & 7) * 8;
        unsigned short u[8];
#pragma unroll
        for (int i = 0; i < 8; i++) u[i] = Ls[ss + i][d];
        *(uint4*)&dst[(size_t)d * S_ + s0 + ss] = *(uint4*)u;
    }
}

// ---- m97-style 128x128-tile bf16 GEMM: C = A @ W^T, A [Mrows][2048] bf16,
// Bw [2048][2048] bf16 row-major. global_load_lds staging + XOR-swizzled reads.
// dstMode 0: fp32 dst[m*2048+n] (m from grid; caller offsets dst).
// dstMode 1: fp32 head-layout, m global over B*S.
// dstMode 3: bf16 dst[m*2048+n].
__global__ __launch_bounds__(256) void gemm128(const unsigned short* __restrict__ A,
                                               const unsigned short* __restrict__ Bw,
                                               void* __restrict__ dst, int dstMode) {
    __shared__ __align__(16) unsigned short As[128][32];
    __shared__ __align__(16) unsigned short Bs[128][32];
    int t = threadIdx.x;
    int wave = t >> 6, lane = t & 63;
    int quad = lane >> 4, l16 = lane & 15;
    int wr = wave >> 1, wc = wave & 1;

    floatx4 acc[4][4];
#pragma unroll
    for (int m = 0; m < 4; m++)
#pragma unroll
        for (int n = 0; n < 4; n++) acc[m][n] = (floatx4)(0.f);

    int srow = lane >> 2;   // 0..15 within a 16-row group
    int sg = lane & 3;      // 16B granule within a 64B row
    const size_t aRow0 = (size_t)blockIdx.x * 128;
    const size_t bRow0 = (size_t)blockIdx.y * 128;

    for (int k0 = 0; k0 < E_; k0 += 32) {
#pragma unroll
        for (int i = 0; i < 2; i++) {
            int lr = wave * 32 + i * 16 + srow;
            int gg = sg ^ ((lr >> 1) & 3);          // inverse swizzle on source
            gload_lds16(A + (aRow0 + lr) * E_ + k0 + gg * 8, &As[wave * 32 + i * 16][0]);
            gload_lds16(Bw + (bRow0 + lr) * E_ + k0 + gg * 8, &Bs[wave * 32 + i * 16][0]);
        }
        __syncthreads();
        short8 af[4], bfr[4];
#pragma unroll
        for (int m = 0; m < 4; m++) {
            int r = wr * 64 + m * 16 + l16;
            af[m] = *(const short8*)((const char*)As + r * 64 + ((quad ^ ((r >> 1) & 3)) << 4));
        }
#pragma unroll
        for (int n = 0; n < 4; n++) {
            int r = wc * 64 + n * 16 + l16;
            bfr[n] = *(const short8*)((const char*)Bs + r * 64 + ((quad ^ ((r >> 1) & 3)) << 4));
        }
#pragma unroll
        for (int m = 0; m < 4; m++)
#pragma unroll
            for (int n = 0; n < 4; n++)
                acc[m][n] = __builtin_amdgcn_mfma_f32_16x16x32_bf16(af[m], bfr[n], acc[m][n], 0, 0, 0);
        __syncthreads();
    }
#pragma unroll
    for (int m = 0; m < 4; m++)
#pragma unroll
        for (int n = 0; n < 4; n++)
#pragma unroll
            for (int rr = 0; rr < 4; rr++) {
                int mg = (int)aRow0 + wr * 64 + m * 16 + quad * 4 + rr;
                int ng = (int)bRow0 + wc * 64 + n * 16 + l16;
                float val = acc[m][n][rr];
                if (dstMode == 0) {
                    ((float*)dst)[(size_t)mg * E_ + ng] = val;
                } else if (dstMode == 1) {
                    int b = mg >> 11, s = mg & 2047, h = ng >> 7, d = ng & 127;
                    ((float*)dst)[(((size_t)(b * H_ + h)) * S_ + s) * D_ + d] = val;
                } else {
                    ((unsigned short*)dst)[(size_t)mg * E_ + ng] = f2bf(val);
                }
            }
}

// ---- Flash attention from precomputed Kr (roped bf16 [B][H][S][D]) and
// Vt (bf16 [B][H][D][S]). Staging = pure global_load_lds; swizzled LDS.
// Grid (512, B): blockIdx.x remapped so each XCD owns 2 heads (L2-resident
// K/V) with qtile descending (LPT balancing of causal work).
__global__ __launch_bounds__(256) void attn_fast(const unsigned short* __restrict__ Qf,
                                                 const unsigned short* __restrict__ Kr,
                                                 const unsigned short* __restrict__ Vt,
                                                 const float* __restrict__ cosT,
                                                 const float* __restrict__ sinT,
                                                 unsigned short* __restrict__ Omid) {
    __shared__ __align__(16) unsigned short Ks[64][128];
    __shared__ __align__(16) unsigned short Vs[128][64];
    __shared__ __align__(16) unsigned short Ps[4][16][72];

    int t = threadIdx.x;
    int wave = t >> 6, lane = t & 63;
    int quad = lane >> 4, l16 = lane & 15;
    int orig = blockIdx.x;                      // 0..511
    int L = (orig & 7) * 64 + (orig >> 3);      // XCD-chunked bijection
    int h = L >> 5;
    int qtile = 31 - (L & 31);                  // heavy tiles first
    int b = blockIdx.y;

    const unsigned short* Qb = Qf + (size_t)b * S_ * E_;
    const unsigned short* Kh = Kr + ((size_t)(b * H_ + h)) * S_ * D_;
    const unsigned short* Vh = Vt + ((size_t)(b * H_ + h)) * D_ * S_;

    // Q fragments (A-operand: row=l16, k=quad*8+j), roped in-register.
    int sq = qtile * 64 + wave * 16 + l16;
    short8 qf[4];
#pragma unroll
    for (int ks = 0; ks < 4; ks++) {
        int d0 = ks * 32 + quad * 8;
        union { uint4 u4; unsigned short u[8]; } un;
        un.u4 = *(const uint4*)&Qb[(size_t)sq * E_ + h * D_ + d0];
#pragma unroll
        for (int i = 0; i < 4; i++) {
            int j = (d0 >> 1) + i;
            float c = cosT[sq * 64 + j], s = sinT[sq * 64 + j];
            float x1 = bf2f(un.u[2 * i]), x2 = bf2f(un.u[2 * i + 1]);
            un.u[2 * i] = f2bf(x1 * c - x2 * s);
            un.u[2 * i + 1] = f2bf(x1 * s + x2 * c);
        }
        qf[ks] = *(short8*)un.u;
    }

    floatx4 O[8];
#pragma unroll
    for (int i = 0; i < 8; i++) O[i] = (floatx4)(0.f);
    float mrow[4], lrow[4];
#pragma unroll
    for (int r = 0; r < 4; r++) { mrow[r] = NEG_S; lrow[r] = 0.f; }

    const float scale = 0.08838834764831845f; // 1/sqrt(128)

    for (int kt = 0; kt <= qtile; kt++) {
        // Stage K tile (64x128 bf16) and V slice (128x64 bf16), linear LDS,
        // inverse-swizzled global source (granule ^= row&7).
#pragma unroll
        for (int i = 0; i < 4; i++) {
            int r = wave * 16 + i * 4 + (lane >> 4);          // K local row 0..63
            int g = (lane & 15) ^ (r & 7);
            gload_lds16(&Kh[(size_t)(kt * 64 + r) * D_ + g * 8], &Ks[wave * 16 + i * 4][0]);
        }
#pragma unroll
        for (int i = 0; i < 4; i++) {
            int r = wave * 32 + i * 8 + (lane >> 3);          // V d-row 0..127
            int g = (lane & 7) ^ (r & 7);
            gload_lds16(&Vh[(size_t)r * S_ + kt * 64 + g * 8], &Vs[wave * 32 + i * 8][0]);
        }
        __syncthreads();

        // S = Q K^T (per wave: 16 rows x 64 cols)
        floatx4 sc[4];
#pragma unroll
        for (int ct = 0; ct < 4; ct++) sc[ct] = (floatx4)(0.f);
#pragma unroll
        for (int ks = 0; ks < 4; ks++) {
#pragma unroll
            for (int ct = 0; ct < 4; ct++) {
                int r = ct * 16 + l16;
                short8 kf = *(const short8*)((const char*)Ks + r * 256 +
                                             ((((ks << 2) + quad) ^ (r & 7)) << 4));
                sc[ct] = __builtin_amdgcn_mfma_f32_16x16x32_bf16(qf[ks], kf, sc[ct], 0, 0, 0);
            }
        }
        // scale + causal mask
        int rowbase = qtile * 64 + wave * 16 + quad * 4;
#pragma unroll
        for (int ct = 0; ct < 4; ct++) {
            int col = kt * 64 + ct * 16 + l16;
#pragma unroll
            for (int rr = 0; rr < 4; rr++) {
                float x = sc[ct][rr] * scale;
                sc[ct][rr] = (col > rowbase + rr) ? NEG_S : x;
            }
        }
        // online softmax (row reductions across 16 lanes of each quad-row)
        float alpha[4];
#pragma unroll
        for (int rr = 0; rr < 4; rr++) {
            float mx = fmaxf(fmaxf(sc[0][rr], sc[1][rr]), fmaxf(sc[2][rr], sc[3][rr]));
            mx = fmaxf(mx, __shfl_xor(mx, 1));
            mx = fmaxf(mx, __shfl_xor(mx, 2));
            mx = fmaxf(mx, __shfl_xor(mx, 4));
            mx = fmaxf(mx, __shfl_xor(mx, 8));
            float mnew = fmaxf(mrow[rr], mx);
            alpha[rr] = exp2f((mrow[rr] - mnew) * LOG2E);
            mrow[rr] = mnew;
        }
#pragma unroll
        for (int rr = 0; rr < 4; rr++) {
            float ps = 0.f;
#pragma unroll
            for (int ct = 0; ct < 4; ct++) {
                float p = exp2f((sc[ct][rr] - mrow[rr]) * LOG2E);
                sc[ct][rr] = p;
                ps += p;
            }
            ps += __shfl_xor(ps, 1);
            ps += __shfl_xor(ps, 2);
            ps += __shfl_xor(ps, 4);
            ps += __shfl_xor(ps, 8);
            lrow[rr] = lrow[rr] * alpha[rr] + ps;
        }
#pragma unroll
        for (int c8 = 0; c8 < 8; c8++)
#pragma unroll
            for (int rr = 0; rr < 4; rr++) O[c8][rr] *= alpha[rr];

        // P: C-layout -> per-wave LDS slice -> A-layout (intra-wave only)
#pragma unroll
        for (int ct = 0; ct < 4; ct++)
#pragma unroll
            for (int rr = 0; rr < 4; rr++)
                Ps[wave][quad * 4 + rr][ct * 16 + l16] = f2bf(sc[ct][rr]);
        asm volatile("s_waitcnt lgkmcnt(0)" ::: "memory");
        __builtin_amdgcn_sched_barrier(0);

        // O += P V
#pragma unroll
        for (int ka2 = 0; ka2 < 2; ka2++) {
            short8 pa = *(const short8*)&Ps[wave][l16][ka2 * 32 + quad * 8];
#pragma unroll
            for (int c8 = 0; c8 < 8; c8++) {
                int r = c8 * 16 + l16;
                short8 vf = *(const short8*)((const char*)Vs + r * 128 +
                                             ((((ka2 << 2) + quad) ^ (r & 7)) << 4));
                O[c8] = __builtin_amdgcn_mfma_f32_16x16x32_bf16(pa, vf, O[c8], 0, 0, 0);
            }
        }
        asm volatile("s_waitcnt lgkmcnt(0)" ::: "memory");
        __builtin_amdgcn_sched_barrier(0);
        __syncthreads();   // all Ks/Vs reads done before restage
    }

    // normalize + store bf16 to mid (full-batch layout)
#pragma unroll
    for (int rr = 0; rr < 4; rr++) {
        float inv = 1.f / lrow[rr];
        int row = qtile * 64 + wave * 16 + quad * 4 + rr;
#pragma unroll
        for (int c8 = 0; c8 < 8; c8++) {
            int d = c8 * 16 + l16;
            Omid[((size_t)b * S_ + row) * E_ + h * D_ + d] = f2bf(O[c8][rr] * inv);
        }
    }
}

// =================== legacy fallback kernels (previous passing version) ====

__global__ __launch_bounds__(256) void gemm_bt(const void* __restrict__ A,
                                               const float* __restrict__ Bw,
                                               void* __restrict__ dst,
                                               int aBf16, int dstMode) {
    __shared__ __align__(16) unsigned short As[64][40];
    __shared__ __align__(16) unsigned short Bs[64][40];
    int t = threadIdx.x;
    int wave = t >> 6, lane = t & 63;
    int quad = lane >> 4, l16 = lane & 15;
    floatx4 acc[4];
#pragma unroll
    for (int i = 0; i < 4; i++) acc[i] = (floatx4)(0.f);

    int r = t >> 2, kc = (t & 3) * 8;
    int ra = blockIdx.x * 64 + r;
    int rb = blockIdx.y * 64 + r;

    for (int k0 = 0; k0 < E_; k0 += 32) {
        if (aBf16) {
            const unsigned short* Ab = (const unsigned short*)A + (size_t)ra * E_ + kc + k0;
            *(uint4*)&As[r][kc] = *(const uint4*)Ab;
        } else {
            const float* Af = (const float*)A + (size_t)ra * E_ + kc + k0;
            float4 f0 = *(const float4*)Af;
            float4 f1 = *(const float4*)(Af + 4);
            unsigned short u[8] = {f2bf(f0.x), f2bf(f0.y), f2bf(f0.z), f2bf(f0.w),
                                   f2bf(f1.x), f2bf(f1.y), f2bf(f1.z), f2bf(f1.w)};
            *(uint4*)&As[r][kc] = *(uint4*)u;
        }
        {
            const float* Bf = Bw + (size_t)rb * E_ + kc + k0;
            float4 g0 = *(const float4*)Bf;
            float4 g1 = *(const float4*)(Bf + 4);
            unsigned short u[8] = {f2bf(g0.x), f2bf(g0.y), f2bf(g0.z), f2bf(g0.w),
                                   f2bf(g1.x), f2bf(g1.y), f2bf(g1.z), f2bf(g1.w)};
            *(uint4*)&Bs[r][kc] = *(uint4*)u;
        }
        __syncthreads();
        short8 a = *(const short8*)&As[wave * 16 + l16][quad * 8];
#pragma unroll
        for (int ct = 0; ct < 4; ct++) {
            short8 bfr = *(const short8*)&Bs[ct * 16 + l16][quad * 8];
            acc[ct] = __builtin_amdgcn_mfma_f32_16x16x32_bf16(a, bfr, acc[ct], 0, 0, 0);
        }
        __syncthreads();
    }
#pragma unroll
    for (int ct = 0; ct < 4; ct++) {
#pragma unroll
        for (int rr = 0; rr < 4; rr++) {
            int m = blockIdx.x * 64 + wave * 16 + quad * 4 + rr;
            int n = blockIdx.y * 64 + ct * 16 + l16;
            float val = acc[ct][rr];
            if (dstMode == 0) {
                ((float*)dst)[(size_t)m * E_ + n] = val;
            } else if (dstMode == 1) {
                int b = m >> 11, s = m & 2047, h = n >> 7, d = n & 127;
                ((float*)dst)[(((size_t)(b * H_ + h)) * S_ + s) * D_ + d] = val;
            } else {
                ((unsigned short*)dst)[(size_t)m * E_ + n] = f2bf(val);
            }
        }
    }
}

__global__ __launch_bounds__(256) void attn_fwd(const unsigned short* __restrict__ Qf,
                                                const float* __restrict__ Kb0,
                                                const float* __restrict__ Vb0,
                                                const float* __restrict__ cosT,
                                                const float* __restrict__ sinT,
                                                unsigned short* __restrict__ Omid,
                                                int qtile0) {
    __shared__ __align__(16) unsigned short Ks[64][136];
    __shared__ __align__(16) unsigned short Vt[128][72];
    __shared__ __align__(16) unsigned short Ps[4][16][72];

    int t = threadIdx.x;
    int wave = t >> 6, lane = t & 63;
    int quad = lane >> 4, l16 = lane & 15;
    int qtile = qtile0 + blockIdx.x, h = blockIdx.y;
    const float* Kb = Kb0 + (size_t)h * S_ * D_;
    const float* Vb = Vb0 + (size_t)h * S_ * D_;

    int sq = qtile * 64 + wave * 16 + l16;
    short8 qf[4];
#pragma unroll
    for (int ks = 0; ks < 4; ks++) {
        int d0 = ks * 32 + quad * 8;
        union { uint4 u4; unsigned short u[8]; } un;
        un.u4 = *(const uint4*)&Qf[(size_t)sq * E_ + h * D_ + d0];
#pragma unroll
        for (int i = 0; i < 4; i++) {
            int j = (d0 >> 1) + i;
            float c = cosT[sq * 64 + j], s = sinT[sq * 64 + j];
            float x1 = bf2f(un.u[2 * i]), x2 = bf2f(un.u[2 * i + 1]);
            un.u[2 * i] = f2bf(x1 * c - x2 * s);
            un.u[2 * i + 1] = f2bf(x1 * s + x2 * c);
        }
        qf[ks] = *(short8*)un.u;
    }

    floatx4 O[8];
#pragma unroll
    for (int i = 0; i < 8; i++) O[i] = (floatx4)(0.f);
    float mrow[4], lrow[4];
#pragma unroll
    for (int r = 0; r < 4; r++) { mrow[r] = NEG_S; lrow[r] = 0.f; }

    const float scale = 0.08838834764831845f;

    for (int kt = 0; kt <= qtile; kt++) {
        __syncthreads();
        int r = t >> 2;
#pragma unroll
        for (int it = 0; it < 4; it++) {
            int d0 = (t & 3) * 8 + it * 32;
            int sk = kt * 64 + r;
            float4 ka = *(const float4*)&Kb[(size_t)sk * D_ + d0];
            float4 kb2 = *(const float4*)&Kb[(size_t)sk * D_ + d0 + 4];
            float xs[8] = {ka.x, ka.y, ka.z, ka.w, kb2.x, kb2.y, kb2.z, kb2.w};
            unsigned short u[8];
#pragma unroll
            for (int i = 0; i < 4; i++) {
                int j = (d0 >> 1) + i;
                float c = cosT[sk * 64 + j], s = sinT[sk * 64 + j];
                float x1 = xs[2 * i], x2 = xs[2 * i + 1];
                u[2 * i]     = f2bf(x1 * c - x2 * s);
                u[2 * i + 1] = f2bf(x1 * s + x2 * c);
            }
            *(uint4*)&Ks[r][d0] = *(uint4*)u;
            float4 va = *(const float4*)&Vb[(size_t)sk * D_ + d0];
            float4 vb2 = *(const float4*)&Vb[(size_t)sk * D_ + d0 + 4];
            float vs[8] = {va.x, va.y, va.z, va.w, vb2.x, vb2.y, vb2.z, vb2.w};
#pragma unroll
            for (int i = 0; i < 8; i++) Vt[d0 + i][r] = f2bf(vs[i]);
        }
        __syncthreads();

        floatx4 sc[4];
#pragma unroll
        for (int ct = 0; ct < 4; ct++) sc[ct] = (floatx4)(0.f);
#pragma unroll
        for (int ks = 0; ks < 4; ks++) {
#pragma unroll
            for (int ct = 0; ct < 4; ct++) {
                short8 kf = *(const short8*)&Ks[ct * 16 + l16][ks * 32 + quad * 8];
                sc[ct] = __builtin_amdgcn_mfma_f32_16x16x32_bf16(qf[ks], kf, sc[ct], 0, 0, 0);
            }
        }
        int rowbase = qtile * 64 + wave * 16 + quad * 4;
#pragma unroll
        for (int ct = 0; ct < 4; ct++) {
            int col = kt * 64 + ct * 16 + l16;
#pragma unroll
            for (int rr = 0; rr < 4; rr++) {
                float x = sc[ct][rr] * scale;
                sc[ct][rr] = (col > rowbase + rr) ? NEG_S : x;
            }
        }
        float alpha[4];
#pragma unroll
        for (int rr = 0; rr < 4; rr++) {
            float mx = fmaxf(fmaxf(sc[0][rr], sc[1][rr]), fmaxf(sc[2][rr], sc[3][rr]));
            mx = fmaxf(mx, __shfl_xor(mx, 1));
            mx = fmaxf(mx, __shfl_xor(mx, 2));
            mx = fmaxf(mx, __shfl_xor(mx, 4));
            mx = fmaxf(mx, __shfl_xor(mx, 8));
            float mnew = fmaxf(mrow[rr], mx);
            alpha[rr] = exp2f((mrow[rr] - mnew) * LOG2E);
            mrow[rr] = mnew;
        }
#pragma unroll
        for (int rr = 0; rr < 4; rr++) {
            float ps = 0.f;
#pragma unroll
            for (int ct = 0; ct < 4; ct++) {
                float p = exp2f((sc[ct][rr] - mrow[rr]) * LOG2E);
                sc[ct][rr] = p;
                ps += p;
            }
            ps += __shfl_xor(ps, 1);
            ps += __shfl_xor(ps, 2);
            ps += __shfl_xor(ps, 4);
            ps += __shfl_xor(ps, 8);
            lrow[rr] = lrow[rr] * alpha[rr] + ps;
        }
#pragma unroll
        for (int c8 = 0; c8 < 8; c8++)
#pragma unroll
            for (int rr = 0; rr < 4; rr++) O[c8][rr] *= alpha[rr];

#pragma unroll
        for (int ct = 0; ct < 4; ct++)
#pragma unroll
            for (int rr = 0; rr < 4; rr++)
                Ps[wave][quad * 4 + rr][ct * 16 + l16] = f2bf(sc[ct][rr]);
        __syncthreads();

#pragma unroll
        for (int ka2 = 0; ka2 < 2; ka2++) {
            short8 pa = *(const short8*)&Ps[wave][l16][ka2 * 32 + quad * 8];
#pragma unroll
            for (int c8 = 0; c8 < 8; c8++) {
                short8 vf = *(const short8*)&Vt[c8 * 16 + l16][ka2 * 32 + quad * 8];
                O[c8] = __builtin_amdgcn_mfma_f32_16x16x32_bf16(pa, vf, O[c8], 0, 0, 0);
            }
        }
    }

#pragma unroll
    for (int rr = 0; rr < 4; rr++) {
        float inv = 1.f / lrow[rr];
        int lrw = blockIdx.x * 64 + wave * 16 + quad * 4 + rr;
#pragma unroll
        for (int c8 = 0; c8 < 8; c8++) {
            int d = c8 * 16 + l16;
            Omid[(size_t)lrw * E_ + h * D_ + d] = f2bf(O[c8][rr] * inv);
        }
    }
}

extern "C" void kernel_launch(void* const* d_in, const int* in_sizes, int n_in,
                              void* d_out, int out_size, void* d_ws, size_t ws_size,
                              hipStream_t stream) {
    const float* x  = (const float*)d_in[0];
    const float* Wq = (const float*)d_in[1];
    const float* Wk = (const float*)d_in[2];
    const float* Wv = (const float*)d_in[3];
    const float* Wo = (const float*)d_in[4];

    float* out_attn = (float*)d_out;                              // (B,S,E) fp32
    float* out_k = out_attn + (size_t)B_ * H_ * S_ * D_;          // (B,H,S,D) fp32 pre-rope
    float* out_v = out_k + (size_t)B_ * H_ * S_ * D_;             // (B,H,S,D) fp32

    char* ws = (char*)d_ws;
    float* cosT = (float*)ws;
    float* sinT = cosT + S_ * (D_ / 2);
    size_t tab_bytes = 2u * S_ * (D_ / 2) * sizeof(float);        // 1 MB

    size_t krBytes  = (size_t)B_ * H_ * S_ * D_ * 2;              // 16.8 MB
    size_t wbBytes  = (size_t)E_ * E_ * 2;                        // 8.4 MB
    size_t midBytes = (size_t)B_ * S_ * E_ * 2;                   // 16.8 MB
    size_t needFast = tab_bytes + 2 * krBytes + wbBytes + midBytes; // ~59.8 MB

    hipLaunchKernelGGL(rope_tab, dim3(512), dim3(256), 0, stream, cosT, sinT);

    if (ws_size >= needFast) {
        // ---------------- fast path ----------------
        unsigned short* Kr  = (unsigned short*)(ws + tab_bytes);
        unsigned short* Vt  = Kr + (size_t)B_ * H_ * S_ * D_;
        unsigned short* Wb  = Vt + (size_t)B_ * H_ * S_ * D_;
        unsigned short* mid = Wb + (size_t)E_ * E_;
        // x_bf16 lives in the front half of out_attn (dead until the Wo GEMM,
        // which is the last launch). q_tmp bf16 in the back half (as before).
        unsigned short* xb    = (unsigned short*)out_attn;                       // [0,16.8M)
        unsigned short* q_tmp = (unsigned short*)(out_attn + (size_t)S_ * E_);   // [16.8,33.5M)

        hipLaunchKernelGGL(cvt_bf16, dim3(4096), dim3(256), 0, stream, x, xb, 1048576);

        hipLaunchKernelGGL(cvt_bf16, dim3(2048), dim3(256), 0, stream, Wq, Wb, 524288);
        hipLaunchKernelGGL(gemm128, dim3(32, 16), dim3(256), 0, stream, xb, Wb, (void*)q_tmp, 3);

        hipLaunchKernelGGL(cvt_bf16, dim3(2048), dim3(256), 0, stream, Wk, Wb, 524288);
        hipLaunchKernelGGL(gemm128, dim3(32, 16), dim3(256), 0, stream, xb, Wb, (void*)out_k, 1);
        hipLaunchKernelGGL(prep_k, dim3(4096), dim3(256), 0, stream, out_k, Kr, cosT, sinT);

        hipLaunchKernelGGL(cvt_bf16, dim3(2048), dim3(256), 0, stream, Wv, Wb, 524288);
        hipLaunchKernelGGL(gemm128, dim3(32, 16), dim3(256), 0, stream, xb, Wb, (void*)out_v, 1);
        hipLaunchKernelGGL(prep_v, dim3(32, 32), dim3(256), 0, stream, out_v, Vt);

        hipLaunchKernelGGL(cvt_bf16, dim3(2048), dim3(256), 0, stream, Wo, Wb, 524288);

        hipLaunchKernelGGL(attn_fast, dim3(512, B_), dim3(256), 0, stream,
                           q_tmp, Kr, Vt, cosT, sinT, mid);
        // final projection over all 4096 rows; clobbers xb/q_tmp (both dead)
        hipLaunchKernelGGL(gemm128, dim3(32, 16), dim3(256), 0, stream, mid, Wb,
                           (void*)out_attn, 0);
    } else {
        // ---------------- legacy fallback (previous passing version) -------
        unsigned short* q_tmp = (unsigned short*)(out_attn + (size_t)S_ * E_);
        unsigned short* mid = (unsigned short*)(ws + tab_bytes);
        size_t avail = ws_size > tab_bytes ? ws_size - tab_bytes : 0;
        int R = 64;
        for (int r = 2048; r >= 64; r >>= 1) {
            if ((size_t)r * E_ * 2 <= avail) { R = r; break; }
        }

        dim3 gg(64, 32);
        hipLaunchKernelGGL(gemm_bt, gg, dim3(256), 0, stream, (const void*)x, Wq, (void*)q_tmp, 0, 3);
        hipLaunchKernelGGL(gemm_bt, gg, dim3(256), 0, stream, (const void*)x, Wk, (void*)out_k, 0, 1);
        hipLaunchKernelGGL(gemm_bt, gg, dim3(256), 0, stream, (const void*)x, Wv, (void*)out_v, 0, 1);

        const size_t bhsd = (size_t)H_ * S_ * D_;
        for (int b = 0; b < B_; b++) {
            const unsigned short* qb = q_tmp + (size_t)b * S_ * E_;
            for (int c = 0; c < S_ / 64; c += R / 64) {
                hipLaunchKernelGGL(attn_fwd, dim3(R / 64, H_), dim3(256), 0, stream,
                                   qb, out_k + b * bhsd, out_v + b * bhsd,
                                   cosT, sinT, mid, c);
                hipLaunchKernelGGL(gemm_bt, dim3(R / 64, 32), dim3(256), 0, stream,
                                   (const void*)mid, Wo,
                                   (void*)(out_attn + ((size_t)b * S_ + c * 64) * E_), 1, 0);
            }
        }
    }
}